// Round 4
// baseline (465.176 us; speedup 1.0000x reference)
//
#include <hip/hip_runtime.h>

#define NB 128
#define SSEQ 1024
#define TD 512
#define TSTR 516   // ts row stride (halfs): 258 dw == 2 mod 4 -> PV gather quad-alias 2-way (free)

typedef _Float16 half8 __attribute__((ext_vector_type(8)));
typedef _Float16 half4 __attribute__((ext_vector_type(4)));
typedef float f32x4 __attribute__((ext_vector_type(4)));

// ---------------- shared NT GEMM body, fp16 MFMA, fp32 accum, fused dtype convert ----------------
// C[m][n] = sum_k A[m][k]*B[n][k]; 64x64 tile, 4 waves. LDS comes from caller's smem pool
// (18432 B) so multi-path kernels can overlay it with other stage layouts.
// AM: 0 = A fp16, 1 = A fp32 (convert in staging), 2 = A fp32 scaled by 1/aRowScale[row*8+sp],
//     3 = A fp32 with relu+convert in staging
// BM: 0 = B fp16, 1 = B fp32
// outMode: 0 = fp32 store, 1 = fp16 store, 2 = fp32 store to outF + sp*oSplit (split-K partials)
//          3 = fp32 atomicAdd into outF (split-K accumulate; bias at sp==0, biasS[sp] per split)
template<int AM, int BM>
__device__ __forceinline__ void gemm_body(
    char* smem,
    const void* __restrict__ Av, int lda, long aSZ,
    const void* __restrict__ Bv, int ldb, long bSZ,
    const float* __restrict__ bias, const float* __restrict__ biasS,
    const float* __restrict__ aRowScale,
    float scale, int doRelu, int outMode,
    float* __restrict__ outF, _Float16* __restrict__ outH,
    int ldc, int cColOff, int kTiles, long oSplit,
    int mt, int nt, int sp, int bz, int tid)
{
  _Float16 (*As)[72] = (_Float16 (*)[72])smem;
  _Float16 (*Bs)[72] = (_Float16 (*)[72])(smem + 9216);
  int r = tid >> 2, kq = (tid & 3) * 16;
  int w = tid >> 6, l = tid & 63;
  long aoff = (long)bz * aSZ + (long)(mt * 64 + r) * lda + (long)sp * kTiles * 64 + kq;
  long boff = (long)bz * bSZ + (long)(nt * 64 + r) * ldb + (long)sp * kTiles * 64 + kq;
  const _Float16* apH = (const _Float16*)Av + aoff;
  const float*    apF = (const float*)Av + aoff;
  const _Float16* bpH = (const _Float16*)Bv + boff;
  const float*    bpF = (const float*)Bv + boff;
  float srA = 1.0f;
  if constexpr (AM == 2) srA = 1.0f / aRowScale[(mt * 64 + r) * 8 + sp];

  half8 pa0, pa1, pb0, pb1;
  f32x4 qa0, qa1, qa2, qa3, qc0, qc1, qc2, qc3;
  if constexpr (AM == 0) { pa0 = *(const half8*)apH; pa1 = *(const half8*)(apH + 8); }
  else { qa0 = *(const f32x4*)apF; qa1 = *(const f32x4*)(apF + 4);
         qa2 = *(const f32x4*)(apF + 8); qa3 = *(const f32x4*)(apF + 12); }
  if constexpr (BM == 0) { pb0 = *(const half8*)bpH; pb1 = *(const half8*)(bpH + 8); }
  else { qc0 = *(const f32x4*)bpF; qc1 = *(const f32x4*)(bpF + 4);
         qc2 = *(const f32x4*)(bpF + 8); qc3 = *(const f32x4*)(bpF + 12); }

  f32x4 acc[4];
  #pragma unroll
  for (int c = 0; c < 4; ++c) acc[c] = (f32x4){0.f, 0.f, 0.f, 0.f};
  int fr = l & 15, fo = (l >> 4) * 8;
  for (int kt = 0; kt < kTiles; ++kt) {
    __syncthreads();
    if constexpr (AM == 0) {
      *(half8*)&As[r][kq] = pa0; *(half8*)&As[r][kq + 8] = pa1;
    } else {
      f32x4 s0 = qa0, s1 = qa1, s2 = qa2, s3 = qa3;
      if constexpr (AM == 2) { s0 *= srA; s1 *= srA; s2 *= srA; s3 *= srA; }
      if constexpr (AM == 3) {
        #pragma unroll
        for (int ii = 0; ii < 4; ++ii) {
          s0[ii] = fmaxf(s0[ii], 0.f); s1[ii] = fmaxf(s1[ii], 0.f);
          s2[ii] = fmaxf(s2[ii], 0.f); s3[ii] = fmaxf(s3[ii], 0.f);
        }
      }
      *(half4*)&As[r][kq + 0]  = __builtin_convertvector(s0, half4);
      *(half4*)&As[r][kq + 4]  = __builtin_convertvector(s1, half4);
      *(half4*)&As[r][kq + 8]  = __builtin_convertvector(s2, half4);
      *(half4*)&As[r][kq + 12] = __builtin_convertvector(s3, half4);
    }
    if constexpr (BM == 0) {
      *(half8*)&Bs[r][kq] = pb0; *(half8*)&Bs[r][kq + 8] = pb1;
    } else {
      *(half4*)&Bs[r][kq + 0]  = __builtin_convertvector(qc0, half4);
      *(half4*)&Bs[r][kq + 4]  = __builtin_convertvector(qc1, half4);
      *(half4*)&Bs[r][kq + 8]  = __builtin_convertvector(qc2, half4);
      *(half4*)&Bs[r][kq + 12] = __builtin_convertvector(qc3, half4);
    }
    __syncthreads();
    if (kt + 1 < kTiles) {
      apH += 64; apF += 64; bpH += 64; bpF += 64;
      if constexpr (AM == 0) { pa0 = *(const half8*)apH; pa1 = *(const half8*)(apH + 8); }
      else { qa0 = *(const f32x4*)apF; qa1 = *(const f32x4*)(apF + 4);
             qa2 = *(const f32x4*)(apF + 8); qa3 = *(const f32x4*)(apF + 12); }
      if constexpr (BM == 0) { pb0 = *(const half8*)bpH; pb1 = *(const half8*)(bpH + 8); }
      else { qc0 = *(const f32x4*)bpF; qc1 = *(const f32x4*)(bpF + 4);
             qc2 = *(const f32x4*)(bpF + 8); qc3 = *(const f32x4*)(bpF + 12); }
    }
    #pragma unroll
    for (int ks = 0; ks < 2; ++ks) {
      half8 af = *(const half8*)&As[16 * w + fr][ks * 32 + fo];
      #pragma unroll
      for (int c = 0; c < 4; ++c) {
        half8 bf = *(const half8*)&Bs[16 * c + fr][ks * 32 + fo];
        acc[c] = __builtin_amdgcn_mfma_f32_16x16x32_f16(af, bf, acc[c], 0, 0, 0);
      }
    }
  }
  int lrow = (l >> 4) * 4, lcol = l & 15;
  #pragma unroll
  for (int c = 0; c < 4; ++c) {
    #pragma unroll
    for (int rr = 0; rr < 4; ++rr) {
      int gm = mt * 64 + 16 * w + lrow + rr;
      int gn = nt * 64 + 16 * c + lcol;
      int ecol = gn + bz * cColOff;
      float vv = acc[c][rr];
      if (bias && sp == 0) vv += bias[ecol];
      if (biasS) vv += biasS[sp * 512 + ecol];
      vv *= scale;
      if (doRelu) vv = fmaxf(vv, 0.f);
      long oidx = (long)gm * ldc + ecol;
      if (outMode == 0) outF[oidx] = vv;
      else if (outMode == 1) outH[oidx] = (_Float16)vv;
      else if (outMode == 2) outF[oidx + (long)sp * oSplit] = vv;
      else atomicAdd(&outF[oidx], vv);
    }
  }
}

template<int AM, int BM>
__global__ __launch_bounds__(256) void k_gemm(
    const void* __restrict__ Av, int lda, long aSZ,
    const void* __restrict__ Bv, int ldb, long bSZ,
    const float* __restrict__ bias, const float* __restrict__ biasS,
    const float* __restrict__ aRowScale,
    float scale, int doRelu, int outMode,
    float* __restrict__ outF, _Float16* __restrict__ outH,
    int ldc, int cColOff, int mtiles, int kTiles, long oSplit)
{
  __shared__ __align__(16) char sm[18432];
  gemm_body<AM, BM>(sm, Av, lda, aSZ, Bv, ldb, bSZ, bias, biasS, aRowScale, scale, doRelu,
                    outMode, outF, outH, ldc, cColOff, kTiles, oSplit,
                    (int)blockIdx.x % mtiles, (int)blockIdx.x / mtiles,
                    (int)blockIdx.y, (int)blockIdx.z, (int)threadIdx.x);
}

// ---------------- prep (blocks 0-511: G + zero chores) + fc1 GEMM (blocks 512-703) ----------------
// G16T[h][g][f] = 0.125*sum_d Wq[64h+d,f]Wk[64h+d,g] (fp16, NT-ready); cvec/gb/qbc bias terms;
// zeroes vsum/pu/pl (contiguous) and qk16 heads 8-15. LDS overlaid: 35.3 KB -> 4 blocks/CU.
__global__ __launch_bounds__(256) void k_prepfc1(
    const float* __restrict__ Wq, const float* __restrict__ Wk,
    const float* __restrict__ bq, const float* __restrict__ bk,
    _Float16* __restrict__ G16T, float* __restrict__ gb,
    float* __restrict__ qbc, float* __restrict__ cvec,
    float* __restrict__ pz, _Float16* __restrict__ qz,
    const float* __restrict__ v, const float* __restrict__ W1,
    const float* __restrict__ b1, _Float16* __restrict__ x16)
{
  __shared__ __align__(16) char sm[35328];
  int bx = blockIdx.x, tid = threadIdx.x;
  if (bx >= 512) {
    int s = bx - 512;   // 192 blocks: mtiles=24, ntiles=8
    gemm_body<1, 1>(sm, v, 768, 0, W1, 768, 0, b1, nullptr, nullptr, 1.f, 1, 1,
                    nullptr, x16, 512, 0, 12, 0, s % 24, s / 24, 0, 0, tid);
    return;
  }
  int b = bx;
  int gid = b * 256 + tid;
  for (long i = gid; i < 147712; i += 131072)   // vsum(65536)+pu(524288)+pl(1024) floats
    *(f32x4*)(pz + 4 * i) = (f32x4){0.f, 0.f, 0.f, 0.f};
  {
    long i4 = (long)gid * 4;
    long n = i4 >> 12, off = i4 & 4095;
    *(half4*)(qz + n * 8192 + 4096 + off) = (half4){(_Float16)0, (_Float16)0, (_Float16)0, (_Float16)0};
  }
  float (*SA)[68] = (float (*)[68])sm;
  float (*SB)[68] = (float (*)[68])(sm + 17408);
  float* sv0 = (float*)(sm + 34816);
  float* sv1 = (float*)(sm + 35072);
  int r = tid >> 2, cq = (tid & 3) * 16;
  int te = tid & 15, td = tid >> 4;
  int h = b >> 6, et = (b >> 3) & 7, dt = b & 7;
  const float* wqp = Wq + (long)(h * 64 + r) * 512 + et * 64 + cq;
  const float* wkp = Wk + (long)(h * 64 + r) * 512 + dt * 64 + cq;
  #pragma unroll
  for (int c = 0; c < 4; ++c) {
    *(f32x4*)&SA[r][cq + 4 * c] = *(const f32x4*)(wqp + 4 * c);
    *(f32x4*)&SB[r][cq + 4 * c] = *(const f32x4*)(wkp + 4 * c);
  }
  if (tid < 64) { sv0[tid] = bq[h * 64 + tid]; sv1[tid] = bk[h * 64 + tid]; }
  __syncthreads();
  float acc[4][4];
  #pragma unroll
  for (int a = 0; a < 4; ++a)
    #pragma unroll
    for (int d = 0; d < 4; ++d) acc[a][d] = 0.f;
  #pragma unroll 4
  for (int j = 0; j < 64; ++j) {
    f32x4 av = *(const f32x4*)&SA[j][te * 4];
    f32x4 bv4 = *(const f32x4*)&SB[j][td * 4];
    #pragma unroll
    for (int a = 0; a < 4; ++a)
      #pragma unroll
      for (int d = 0; d < 4; ++d) acc[a][d] = fmaf(av[a], bv4[d], acc[a][d]);
  }
  #pragma unroll
  for (int d = 0; d < 4; ++d) {
    half4 hv = { (_Float16)(0.125f * acc[0][d]), (_Float16)(0.125f * acc[1][d]),
                 (_Float16)(0.125f * acc[2][d]), (_Float16)(0.125f * acc[3][d]) };
    *(half4*)(G16T + (long)h * 262144 + (long)(dt * 64 + td * 4 + d) * 512 + et * 64 + te * 4) = hv;
  }
  if (dt == 0 && td == 0) {
    #pragma unroll
    for (int i = 0; i < 4; ++i) {
      float s = 0.f;
      for (int j = 0; j < 64; ++j) s = fmaf(SA[j][te * 4 + i], sv1[j], s);
      gb[h * 512 + et * 64 + te * 4 + i] = 0.125f * s;
    }
  }
  if (et == 0 && te == 0) {
    #pragma unroll
    for (int i = 0; i < 4; ++i) {
      float s = 0.f;
      for (int j = 0; j < 64; ++j) s = fmaf(SB[j][td * 4 + i], sv0[j], s);
      cvec[h * 512 + dt * 64 + td * 4 + i] = 0.125f * s;
    }
  }
  if (et == 0 && dt == 0 && tid == 0) {
    float s = 0.f;
    for (int j = 0; j < 64; ++j) s = fmaf(sv0[j], sv1[j], s);
    qbc[h] = 0.125f * s;
  }
}

// ---------------- k_qkqb: qk GEMM (0-127) + qb/out0/out-zero (128-255) + M-prep (256-767) --------
// qk16 = relu(vsum) @ G16T (+cvec), relu fused into A-staging (AM=3).
// qb blocks: out0 = relu(vsum) (output 0), qb = out0 . gb + qbc, zero attn-out slab.
// M-prep: M16T[e][h*512+g] = sum_d Wv[64h+d,g]Wo[e,64h+d]; obo8[h][e] = sum_d Wo[e,64h+d]bv[64h+d].
// LDS overlaid (35.3 KB max) -> 4 blocks/CU; all 768 blocks co-resident.
__global__ __launch_bounds__(256) void k_qkqb(
    const float* __restrict__ vsum, const _Float16* __restrict__ G16T,
    const float* __restrict__ cvec, const float* __restrict__ gb,
    const float* __restrict__ qbc, _Float16* __restrict__ qk16,
    float* __restrict__ qb, float* __restrict__ outz, float* __restrict__ out0,
    const float* __restrict__ Wv, const float* __restrict__ Wo,
    const float* __restrict__ bv, _Float16* __restrict__ M16,
    float* __restrict__ obo8)
{
  __shared__ __align__(16) char sm[35328];
  int bx = blockIdx.x, tid = threadIdx.x;
  if (bx < 128) {
    int z = bx >> 4, s = bx & 15;   // mtiles=2, ntiles=8, 8 heads
    gemm_body<3, 0>(sm, vsum, 512, 0, G16T, 512, 262144, cvec, nullptr, nullptr, 1.f, 0, 1,
                    nullptr, qk16, 8192, 512, 8, 0, s % 2, s / 2, 0, z, tid);
    return;
  }
  if (bx < 256) {
    int n = bx - 128;
    float* oz = outz + (long)n * 512;    // zero attn-out slab for atomic split-K epilogue
    oz[tid] = 0.f; oz[tid + 256] = 0.f;
    float* qs = (float*)sm;
    float v0 = fmaxf(vsum[n * 512 + tid], 0.f);
    float v1 = fmaxf(vsum[n * 512 + tid + 256], 0.f);
    out0[n * 512 + tid] = v0;            // output 0 = vfeat
    out0[n * 512 + tid + 256] = v1;
    qs[tid] = v0; qs[tid + 256] = v1;
    __syncthreads();
    int h = tid >> 5, j = tid & 31;
    float p = 0.f;
    for (int e = j; e < 512; e += 32) p = fmaf(qs[e], gb[h * 512 + e], p);
    #pragma unroll
    for (int m = 1; m < 32; m <<= 1) p += __shfl_xor(p, m, 32);
    if (j == 0) qb[n * 8 + h] = p + qbc[h];
    return;
  }
  // ---- M-prep ----
  int b2i = bx - 256;
  int h = b2i >> 6, et = (b2i >> 3) & 7, gt = b2i & 7;
  float (*SA)[68] = (float (*)[68])sm;
  float (*SB)[68] = (float (*)[68])(sm + 17408);
  float* sv0 = (float*)(sm + 34816);
  int r = tid >> 2, cq = (tid & 3) * 16;
  int te = tid & 15, td = tid >> 4;
  const float* wvp = Wv + (long)(h * 64 + r) * 512 + gt * 64 + cq;
  const float* wop = Wo + (long)(et * 64 + r) * 512 + h * 64 + cq;
  #pragma unroll
  for (int c = 0; c < 4; ++c)
    *(f32x4*)&SA[r][cq + 4 * c] = *(const f32x4*)(wvp + 4 * c);   // SA[d][g]
  #pragma unroll
  for (int c = 0; c < 4; ++c) {
    f32x4 x = *(const f32x4*)(wop + 4 * c);                       // coalesced Wo rows
    #pragma unroll
    for (int i = 0; i < 4; ++i) SB[cq + 4 * c + i][r] = x[i];     // SB[d][e] (transposed store)
  }
  if (tid < 64) sv0[tid] = bv[h * 64 + tid];
  __syncthreads();
  float acc[4][4];
  #pragma unroll
  for (int a = 0; a < 4; ++a)
    #pragma unroll
    for (int d = 0; d < 4; ++d) acc[a][d] = 0.f;
  #pragma unroll 4
  for (int jj = 0; jj < 64; ++jj) {
    f32x4 av = *(const f32x4*)&SA[jj][te * 4];
    f32x4 bt = *(const f32x4*)&SB[jj][td * 4];
    #pragma unroll
    for (int a = 0; a < 4; ++a)
      #pragma unroll
      for (int d = 0; d < 4; ++d) acc[a][d] = fmaf(av[a], bt[d], acc[a][d]);
  }
  #pragma unroll
  for (int d = 0; d < 4; ++d) {
    half4 hv = { (_Float16)acc[0][d], (_Float16)acc[1][d],
                 (_Float16)acc[2][d], (_Float16)acc[3][d] };
    *(half4*)(M16 + (long)(et * 64 + td * 4 + d) * 4096 + h * 512 + gt * 64 + te * 4) = hv;
  }
  if (gt == 0 && te == 0) {
    float s0 = 0.f, s1 = 0.f, s2 = 0.f, s3 = 0.f;
    for (int jj = 0; jj < 64; ++jj) {
      f32x4 bt = *(const f32x4*)&SB[jj][td * 4];
      float bb = sv0[jj];
      s0 = fmaf(bt[0], bb, s0); s1 = fmaf(bt[1], bb, s1);
      s2 = fmaf(bt[2], bb, s2); s3 = fmaf(bt[3], bb, s3);
    }
    obo8[h * 512 + et * 64 + td * 4 + 0] = s0;
    obo8[h * 512 + et * 64 + td * 4 + 1] = s1;
    obo8[h * 512 + et * 64 + td * 4 + 2] = s2;
    obo8[h * 512 + et * 64 + td * 4 + 3] = s3;
  }
}

// ---------------- fused streaming attention: 4 stride-interleaved 64-row tiles per block --------
// Block (n,g) owns tiles {g, g+4, g+8, g+12} (stride-4: balances work across the 4 blocks of an n
// for any t_len — all 512 blocks are co-resident, so kernel time = max block time).
// Wave-local staging (no stage barrier); scores on own rows; PV accumulates upv in registers
// across tiles; single pu/pl atomic flush. 2 barriers per tile.
__global__ __launch_bounds__(256) void k_attn(
    const float* __restrict__ t, const int* __restrict__ tlen,
    const _Float16* __restrict__ qk16, const float* __restrict__ qb,
    float* __restrict__ pu, float* __restrict__ pl)
{
  int n = blockIdx.x >> 2, g = blockIdx.x & 3;
  int len = tlen[n];
  if (g * 64 >= len) return;
  int tid = threadIdx.x, wid = tid >> 6, l = tid & 63;
  int fr = l & 15, fo = (l >> 4) * 8;

  __shared__ __align__(16) _Float16 ts[64][TSTR];   // 64.5 KB
  __shared__ __align__(16) _Float16 wst[16][72];    // stride 36 dw: A-read conflict-free

  const float* tn = t + (long)n * SSEQ * TD;
  const _Float16* qn = qk16 + (long)n * 8192 + fr * 512 + fo;
  float qbr = (fr < 8) ? qb[n * 8 + fr] : 0.f;

  f32x4 upv[8];
  #pragma unroll
  for (int dt = 0; dt < 8; ++dt) upv[dt] = (f32x4){0.f, 0.f, 0.f, 0.f};
  float lsum = 0.f;

  for (int jj = 0; jj < 4; ++jj) {
    int base = (g + 4 * jj) * 64;
    if (base >= len) break;                       // block-uniform
    int s1 = base + 64; if (s1 > len) s1 = len;
    if (jj) __syncthreads();                      // protect ts/wst from previous PV readers
    // ---- wave-local stage: rows 16*wid .. 16*wid+15, fp32->fp16, 2-row pipeline ----
    {
      f32x4 a0, a1, b0, b1;
      auto ld = [&](int rr, f32x4& x0, f32x4& x1) {
        int sg = base + 16 * wid + rr;
        if (sg < s1) {
          const float* p = tn + (long)sg * TD;
          x0 = *(const f32x4*)(p + 4 * l);
          x1 = *(const f32x4*)(p + 256 + 4 * l);
        } else {
          x0 = (f32x4){0.f,0.f,0.f,0.f}; x1 = (f32x4){0.f,0.f,0.f,0.f};
        }
      };
      ld(0, a0, a1); ld(1, b0, b1);
      #pragma unroll
      for (int rr = 0; rr < 16; rr += 2) {
        half4 h0 = __builtin_convertvector(a0, half4);
        half4 h1 = __builtin_convertvector(a1, half4);
        int row = 16 * wid + rr;
        if (rr + 2 < 16) ld(rr + 2, a0, a1);
        *(half4*)&ts[row][4 * l] = h0;
        *(half4*)&ts[row][256 + 4 * l] = h1;
        half4 g0 = __builtin_convertvector(b0, half4);
        half4 g1 = __builtin_convertvector(b1, half4);
        if (rr + 3 < 16) ld(rr + 3, b0, b1);
        *(half4*)&ts[row + 1][4 * l] = g0;
        *(half4*)&ts[row + 1][256 + 4 * l] = g1;
      }
    }
    // ---- scores on own rows (wave-internal LDS dependency; no block barrier) ----
    {
      f32x4 acc = (f32x4){0.f, 0.f, 0.f, 0.f};
      __builtin_amdgcn_s_setprio(1);
      #pragma unroll 4
      for (int kt = 0; kt < 16; ++kt) {
        half8 bf = *(const half8*)(qn + kt * 32);
        const _Float16* ap = &ts[16 * wid + fr][kt * 32 + fo];
        half4 alo = *(const half4*)ap;             // b64 pair (row stride 8-aligned)
        half4 ahi = *(const half4*)(ap + 4);
        half8 af = { alo[0], alo[1], alo[2], alo[3], ahi[0], ahi[1], ahi[2], ahi[3] };
        acc = __builtin_amdgcn_mfma_f32_16x16x32_f16(af, bf, acc, 0, 0, 0);
      }
      __builtin_amdgcn_s_setprio(0);
      #pragma unroll
      for (int r = 0; r < 4; ++r) {
        int sl = 16 * wid + (l >> 4) * 4 + r;
        float wv = (fr < 8 && base + sl < s1) ? __expf(acc[r] + qbr) : 0.f;
        wst[fr][sl] = (_Float16)wv;
        lsum += wv;
      }
    }
    __syncthreads();
    // ---- PV via MFMA: wave owns d-range [128*wid, +128); 8 col-tiles x K=64; acc across jj ----
    __builtin_amdgcn_s_setprio(1);
    #pragma unroll
    for (int dt = 0; dt < 8; ++dt) {
      int dcol = 128 * wid + dt * 16 + fr;
      #pragma unroll
      for (int ks = 0; ks < 2; ++ks) {
        half8 af = *(const half8*)&wst[fr][ks * 32 + fo];
        half8 bf;
        #pragma unroll
        for (int jx = 0; jx < 8; ++jx) bf[jx] = ts[ks * 32 + fo + jx][dcol];
        upv[dt] = __builtin_amdgcn_mfma_f32_16x16x32_f16(af, bf, upv[dt], 0, 0, 0);
      }
    }
    __builtin_amdgcn_s_setprio(0);
  }
  // ---- single flush: lane quad q holds heads 4q..4q+3 (valid q<2) ----
  int quad = l >> 4;
  float* pn = pu + (long)n * 4096;
  if (quad < 2) {
    #pragma unroll
    for (int dt = 0; dt < 8; ++dt) {
      int d = 128 * wid + dt * 16 + fr;
      #pragma unroll
      for (int r = 0; r < 4; ++r)
        atomicAdd(&pn[(quad * 4 + r) * 512 + d], upv[dt][r]);
    }
  }
  if (fr < 8) atomicAdd(&pl[n * 8 + fr], lsum);
}

extern "C" void kernel_launch(void* const* d_in, const int* in_sizes, int n_in,
                              void* d_out, int out_size, void* d_ws, size_t ws_size,
                              hipStream_t stream)
{
  const float* v    = (const float*)d_in[0];
  const float* t    = (const float*)d_in[1];
  const int*   tlen = (const int*)d_in[2];
  const float* W1   = (const float*)d_in[3];
  const float* b1   = (const float*)d_in[4];
  const float* W2   = (const float*)d_in[5];
  const float* b2   = (const float*)d_in[6];
  const float* Wq   = (const float*)d_in[7];
  const float* Wk   = (const float*)d_in[8];
  const float* Wv   = (const float*)d_in[9];
  const float* bq   = (const float*)d_in[10];
  const float* bk   = (const float*)d_in[11];
  const float* bv   = (const float*)d_in[12];
  const float* Wo   = (const float*)d_in[13];
  const float* bo   = (const float*)d_in[14];
  float* out = (float*)d_out;

  // ---- workspace layout: fp16 region then fp32 region (~14.5 MB total) ----
  _Float16* hb   = (_Float16*)d_ws;
  _Float16* x16  = hb;                  // 786432   [1536][512]
  _Float16* qk16 = hb + 786432l;        // 1048576  [128][16][512]
  _Float16* G16T = hb + 1835008l;       // 2097152  [8][512 g][512 f]
  _Float16* M16  = hb + 3932160l;       // 2097152  [512 e][8*512 (h,g)]
  float* fb   = (float*)(hb + 6029312l);
  float* vsum = fb;                     // 65536    [128][512] fc2 atomic accum (zeroed)
  float* pu   = fb + 65536l;            // 524288   [128][8][512] (zeroed)
  float* pl   = fb + 589824l;           // 1024     [128][8]  (zeroed)
  float* qb   = fb + 590848l;           // 1024
  float* gb   = fb + 591872l;           // 4096     [8][512]
  float* qbc  = fb + 595968l;           // 16
  float* cvec = fb + 595984l;           // 4096     [8][512]
  float* obo8 = fb + 600080l;           // 4096     [8][512]

  // prep (G/gb/cvec/qbc + zero vsum/pu/pl/qk16-pad) || fc1 GEMM
  k_prepfc1<<<704, 256, 0, stream>>>(Wq, Wk, bq, bk, G16T, gb, qbc, cvec,
                                     fb, qk16, v, W1, b1, x16);
  // fc2 split-K(8): A=x16 fp16 [128x6144], B=W2 fp32 -> atomic accum into vsum (+b2 at sp0)
  k_gemm<0,1><<<dim3(16, 8, 1), 256, 0, stream>>>(x16, 6144, 0, W2, 6144, 0,
      b2, nullptr, nullptr, 1.f, 0, 3, vsum, nullptr, 512, 0, 2, 12, 0);
  // qk16 = relu(vsum) @ G16T (+cvec) || out0 = relu(vsum), qb, zero out1 || M16/obo8 prep
  k_qkqb<<<768, 256, 0, stream>>>(vsum, G16T, cvec, gb, qbc, qk16, qb,
                                  out + 65536, out, Wv, Wo, bv, M16, obo8);
  k_attn<<<NB * 4, 256, 0, stream>>>(t, tlen, qk16, qb, pu, pl);
  // attn_out = (pu/pl) @ M16 + bo + obo8[sp], split-K over heads, atomic epilogue -> output 1
  k_gemm<2,0><<<dim3(16, 8, 1), 256, 0, stream>>>(pu, 4096, 0, M16, 4096, 0,
      bo, obo8, pl, 1.f, 0, 3, out + 65536, nullptr, 512, 0, 2, 8, 0);
}

// Round 5
// 464.382 us; speedup vs baseline: 1.0017x; 1.0017x over previous
//
#include <hip/hip_runtime.h>

#define NB 128
#define SSEQ 1024
#define TD 512
#define TSTR 516   // ts row stride (halfs): 258 dw == 2 mod 4 -> PV gather quad-alias 2-way (free)

typedef _Float16 half8 __attribute__((ext_vector_type(8)));
typedef _Float16 half4 __attribute__((ext_vector_type(4)));
typedef float f32x4 __attribute__((ext_vector_type(4)));

// ---------------- shared NT GEMM body, fp16 MFMA, fp32 accum, fused dtype convert ----------------
// C[m][n] = sum_k A[m][k]*B[n][k]; 64x64 tile, 4 waves. LDS comes from caller's smem pool
// (18432 B) so multi-path kernels can overlay it with other stage layouts.
// AM: 0 = A fp16, 1 = A fp32 (convert in staging), 2 = A fp32 scaled by 1/aRowScale[row*8+sp],
//     3 = A fp32 with relu+convert in staging
// BM: 0 = B fp16, 1 = B fp32
// outMode: 0 = fp32 store, 1 = fp16 store, 2 = fp32 store to outF + sp*oSplit (split-K partials)
//          3 = fp32 atomicAdd into outF (split-K accumulate; bias at sp==0, biasS[sp] per split)
template<int AM, int BM>
__device__ __forceinline__ void gemm_body(
    char* smem,
    const void* __restrict__ Av, int lda, long aSZ,
    const void* __restrict__ Bv, int ldb, long bSZ,
    const float* __restrict__ bias, const float* __restrict__ biasS,
    const float* __restrict__ aRowScale,
    float scale, int doRelu, int outMode,
    float* __restrict__ outF, _Float16* __restrict__ outH,
    int ldc, int cColOff, int kTiles, long oSplit,
    int mt, int nt, int sp, int bz, int tid)
{
  _Float16 (*As)[72] = (_Float16 (*)[72])smem;
  _Float16 (*Bs)[72] = (_Float16 (*)[72])(smem + 9216);
  int r = tid >> 2, kq = (tid & 3) * 16;
  int w = tid >> 6, l = tid & 63;
  long aoff = (long)bz * aSZ + (long)(mt * 64 + r) * lda + (long)sp * kTiles * 64 + kq;
  long boff = (long)bz * bSZ + (long)(nt * 64 + r) * ldb + (long)sp * kTiles * 64 + kq;
  const _Float16* apH = (const _Float16*)Av + aoff;
  const float*    apF = (const float*)Av + aoff;
  const _Float16* bpH = (const _Float16*)Bv + boff;
  const float*    bpF = (const float*)Bv + boff;
  float srA = 1.0f;
  if constexpr (AM == 2) srA = 1.0f / aRowScale[(mt * 64 + r) * 8 + sp];

  half8 pa0, pa1, pb0, pb1;
  f32x4 qa0, qa1, qa2, qa3, qc0, qc1, qc2, qc3;
  if constexpr (AM == 0) { pa0 = *(const half8*)apH; pa1 = *(const half8*)(apH + 8); }
  else { qa0 = *(const f32x4*)apF; qa1 = *(const f32x4*)(apF + 4);
         qa2 = *(const f32x4*)(apF + 8); qa3 = *(const f32x4*)(apF + 12); }
  if constexpr (BM == 0) { pb0 = *(const half8*)bpH; pb1 = *(const half8*)(bpH + 8); }
  else { qc0 = *(const f32x4*)bpF; qc1 = *(const f32x4*)(bpF + 4);
         qc2 = *(const f32x4*)(bpF + 8); qc3 = *(const f32x4*)(bpF + 12); }

  f32x4 acc[4];
  #pragma unroll
  for (int c = 0; c < 4; ++c) acc[c] = (f32x4){0.f, 0.f, 0.f, 0.f};
  int fr = l & 15, fo = (l >> 4) * 8;
  for (int kt = 0; kt < kTiles; ++kt) {
    __syncthreads();
    if constexpr (AM == 0) {
      *(half8*)&As[r][kq] = pa0; *(half8*)&As[r][kq + 8] = pa1;
    } else {
      f32x4 s0 = qa0, s1 = qa1, s2 = qa2, s3 = qa3;
      if constexpr (AM == 2) { s0 *= srA; s1 *= srA; s2 *= srA; s3 *= srA; }
      if constexpr (AM == 3) {
        #pragma unroll
        for (int ii = 0; ii < 4; ++ii) {
          s0[ii] = fmaxf(s0[ii], 0.f); s1[ii] = fmaxf(s1[ii], 0.f);
          s2[ii] = fmaxf(s2[ii], 0.f); s3[ii] = fmaxf(s3[ii], 0.f);
        }
      }
      *(half4*)&As[r][kq + 0]  = __builtin_convertvector(s0, half4);
      *(half4*)&As[r][kq + 4]  = __builtin_convertvector(s1, half4);
      *(half4*)&As[r][kq + 8]  = __builtin_convertvector(s2, half4);
      *(half4*)&As[r][kq + 12] = __builtin_convertvector(s3, half4);
    }
    if constexpr (BM == 0) {
      *(half8*)&Bs[r][kq] = pb0; *(half8*)&Bs[r][kq + 8] = pb1;
    } else {
      *(half4*)&Bs[r][kq + 0]  = __builtin_convertvector(qc0, half4);
      *(half4*)&Bs[r][kq + 4]  = __builtin_convertvector(qc1, half4);
      *(half4*)&Bs[r][kq + 8]  = __builtin_convertvector(qc2, half4);
      *(half4*)&Bs[r][kq + 12] = __builtin_convertvector(qc3, half4);
    }
    __syncthreads();
    if (kt + 1 < kTiles) {
      apH += 64; apF += 64; bpH += 64; bpF += 64;
      if constexpr (AM == 0) { pa0 = *(const half8*)apH; pa1 = *(const half8*)(apH + 8); }
      else { qa0 = *(const f32x4*)apF; qa1 = *(const f32x4*)(apF + 4);
             qa2 = *(const f32x4*)(apF + 8); qa3 = *(const f32x4*)(apF + 12); }
      if constexpr (BM == 0) { pb0 = *(const half8*)bpH; pb1 = *(const half8*)(bpH + 8); }
      else { qc0 = *(const f32x4*)bpF; qc1 = *(const f32x4*)(bpF + 4);
             qc2 = *(const f32x4*)(bpF + 8); qc3 = *(const f32x4*)(bpF + 12); }
    }
    #pragma unroll
    for (int ks = 0; ks < 2; ++ks) {
      half8 af = *(const half8*)&As[16 * w + fr][ks * 32 + fo];
      #pragma unroll
      for (int c = 0; c < 4; ++c) {
        half8 bf = *(const half8*)&Bs[16 * c + fr][ks * 32 + fo];
        acc[c] = __builtin_amdgcn_mfma_f32_16x16x32_f16(af, bf, acc[c], 0, 0, 0);
      }
    }
  }
  int lrow = (l >> 4) * 4, lcol = l & 15;
  #pragma unroll
  for (int c = 0; c < 4; ++c) {
    #pragma unroll
    for (int rr = 0; rr < 4; ++rr) {
      int gm = mt * 64 + 16 * w + lrow + rr;
      int gn = nt * 64 + 16 * c + lcol;
      int ecol = gn + bz * cColOff;
      float vv = acc[c][rr];
      if (bias && sp == 0) vv += bias[ecol];
      if (biasS) vv += biasS[sp * 512 + ecol];
      vv *= scale;
      if (doRelu) vv = fmaxf(vv, 0.f);
      long oidx = (long)gm * ldc + ecol;
      if (outMode == 0) outF[oidx] = vv;
      else if (outMode == 1) outH[oidx] = (_Float16)vv;
      else if (outMode == 2) outF[oidx + (long)sp * oSplit] = vv;
      else atomicAdd(&outF[oidx], vv);
    }
  }
}

template<int AM, int BM>
__global__ __launch_bounds__(256) void k_gemm(
    const void* __restrict__ Av, int lda, long aSZ,
    const void* __restrict__ Bv, int ldb, long bSZ,
    const float* __restrict__ bias, const float* __restrict__ biasS,
    const float* __restrict__ aRowScale,
    float scale, int doRelu, int outMode,
    float* __restrict__ outF, _Float16* __restrict__ outH,
    int ldc, int cColOff, int mtiles, int kTiles, long oSplit)
{
  __shared__ __align__(16) char sm[18432];
  gemm_body<AM, BM>(sm, Av, lda, aSZ, Bv, ldb, bSZ, bias, biasS, aRowScale, scale, doRelu,
                    outMode, outF, outH, ldc, cColOff, kTiles, oSplit,
                    (int)blockIdx.x % mtiles, (int)blockIdx.x / mtiles,
                    (int)blockIdx.y, (int)blockIdx.z, (int)threadIdx.x);
}

// ---------------- prep (blocks 0-511: G + zero chores) + fc1 GEMM (blocks 512-703) ----------------
// G16T[h][g][f] = 0.125*sum_d Wq[64h+d,f]Wk[64h+d,g] (fp16, NT-ready); cvec/gb/qbc bias terms;
// zeroes vsum/pu/pl (contiguous) and qk16 heads 8-15. LDS overlaid: 35.3 KB -> 4 blocks/CU.
__global__ __launch_bounds__(256) void k_prepfc1(
    const float* __restrict__ Wq, const float* __restrict__ Wk,
    const float* __restrict__ bq, const float* __restrict__ bk,
    _Float16* __restrict__ G16T, float* __restrict__ gb,
    float* __restrict__ qbc, float* __restrict__ cvec,
    float* __restrict__ pz, _Float16* __restrict__ qz,
    const float* __restrict__ v, const float* __restrict__ W1,
    const float* __restrict__ b1, _Float16* __restrict__ x16)
{
  __shared__ __align__(16) char sm[35328];
  int bx = blockIdx.x, tid = threadIdx.x;
  if (bx >= 512) {
    int s = bx - 512;   // 192 blocks: mtiles=24, ntiles=8
    gemm_body<1, 1>(sm, v, 768, 0, W1, 768, 0, b1, nullptr, nullptr, 1.f, 1, 1,
                    nullptr, x16, 512, 0, 12, 0, s % 24, s / 24, 0, 0, tid);
    return;
  }
  int b = bx;
  int gid = b * 256 + tid;
  for (long i = gid; i < 147712; i += 131072)   // vsum(65536)+pu(524288)+pl(1024) floats
    *(f32x4*)(pz + 4 * i) = (f32x4){0.f, 0.f, 0.f, 0.f};
  {
    long i4 = (long)gid * 4;
    long n = i4 >> 12, off = i4 & 4095;
    *(half4*)(qz + n * 8192 + 4096 + off) = (half4){(_Float16)0, (_Float16)0, (_Float16)0, (_Float16)0};
  }
  float (*SA)[68] = (float (*)[68])sm;
  float (*SB)[68] = (float (*)[68])(sm + 17408);
  float* sv0 = (float*)(sm + 34816);
  float* sv1 = (float*)(sm + 35072);
  int r = tid >> 2, cq = (tid & 3) * 16;
  int te = tid & 15, td = tid >> 4;
  int h = b >> 6, et = (b >> 3) & 7, dt = b & 7;
  const float* wqp = Wq + (long)(h * 64 + r) * 512 + et * 64 + cq;
  const float* wkp = Wk + (long)(h * 64 + r) * 512 + dt * 64 + cq;
  #pragma unroll
  for (int c = 0; c < 4; ++c) {
    *(f32x4*)&SA[r][cq + 4 * c] = *(const f32x4*)(wqp + 4 * c);
    *(f32x4*)&SB[r][cq + 4 * c] = *(const f32x4*)(wkp + 4 * c);
  }
  if (tid < 64) { sv0[tid] = bq[h * 64 + tid]; sv1[tid] = bk[h * 64 + tid]; }
  __syncthreads();
  float acc[4][4];
  #pragma unroll
  for (int a = 0; a < 4; ++a)
    #pragma unroll
    for (int d = 0; d < 4; ++d) acc[a][d] = 0.f;
  #pragma unroll 4
  for (int j = 0; j < 64; ++j) {
    f32x4 av = *(const f32x4*)&SA[j][te * 4];
    f32x4 bv4 = *(const f32x4*)&SB[j][td * 4];
    #pragma unroll
    for (int a = 0; a < 4; ++a)
      #pragma unroll
      for (int d = 0; d < 4; ++d) acc[a][d] = fmaf(av[a], bv4[d], acc[a][d]);
  }
  #pragma unroll
  for (int d = 0; d < 4; ++d) {
    half4 hv = { (_Float16)(0.125f * acc[0][d]), (_Float16)(0.125f * acc[1][d]),
                 (_Float16)(0.125f * acc[2][d]), (_Float16)(0.125f * acc[3][d]) };
    *(half4*)(G16T + (long)h * 262144 + (long)(dt * 64 + td * 4 + d) * 512 + et * 64 + te * 4) = hv;
  }
  if (dt == 0 && td == 0) {
    #pragma unroll
    for (int i = 0; i < 4; ++i) {
      float s = 0.f;
      for (int j = 0; j < 64; ++j) s = fmaf(SA[j][te * 4 + i], sv1[j], s);
      gb[h * 512 + et * 64 + te * 4 + i] = 0.125f * s;
    }
  }
  if (et == 0 && te == 0) {
    #pragma unroll
    for (int i = 0; i < 4; ++i) {
      float s = 0.f;
      for (int j = 0; j < 64; ++j) s = fmaf(SB[j][td * 4 + i], sv0[j], s);
      cvec[h * 512 + dt * 64 + td * 4 + i] = 0.125f * s;
    }
  }
  if (et == 0 && dt == 0 && tid == 0) {
    float s = 0.f;
    for (int j = 0; j < 64; ++j) s = fmaf(sv0[j], sv1[j], s);
    qbc[h] = 0.125f * s;
  }
}

// ---------------- k_qkqb: qk GEMM (0-127) + qb/out0/out-zero (128-255) + M-prep (256-767) --------
// qk16 = relu(vsum) @ G16T (+cvec), relu fused into A-staging (AM=3).
// qb blocks: out0 = relu(vsum) (output 0), qb = out0 . gb + qbc, zero attn-out slab.
// M-prep: M16T[e][h*512+g] = sum_d Wv[64h+d,g]Wo[e,64h+d]; obo8[h][e] = sum_d Wo[e,64h+d]bv[64h+d].
// LDS overlaid (35.3 KB max) -> 4 blocks/CU; all 768 blocks co-resident.
__global__ __launch_bounds__(256) void k_qkqb(
    const float* __restrict__ vsum, const _Float16* __restrict__ G16T,
    const float* __restrict__ cvec, const float* __restrict__ gb,
    const float* __restrict__ qbc, _Float16* __restrict__ qk16,
    float* __restrict__ qb, float* __restrict__ outz, float* __restrict__ out0,
    const float* __restrict__ Wv, const float* __restrict__ Wo,
    const float* __restrict__ bv, _Float16* __restrict__ M16,
    float* __restrict__ obo8)
{
  __shared__ __align__(16) char sm[35328];
  int bx = blockIdx.x, tid = threadIdx.x;
  if (bx < 128) {
    int z = bx >> 4, s = bx & 15;   // mtiles=2, ntiles=8, 8 heads
    gemm_body<3, 0>(sm, vsum, 512, 0, G16T, 512, 262144, cvec, nullptr, nullptr, 1.f, 0, 1,
                    nullptr, qk16, 8192, 512, 8, 0, s % 2, s / 2, 0, z, tid);
    return;
  }
  if (bx < 256) {
    int n = bx - 128;
    float* oz = outz + (long)n * 512;    // zero attn-out slab for atomic split-K epilogue
    oz[tid] = 0.f; oz[tid + 256] = 0.f;
    float* qs = (float*)sm;
    float v0 = fmaxf(vsum[n * 512 + tid], 0.f);
    float v1 = fmaxf(vsum[n * 512 + tid + 256], 0.f);
    out0[n * 512 + tid] = v0;            // output 0 = vfeat
    out0[n * 512 + tid + 256] = v1;
    qs[tid] = v0; qs[tid + 256] = v1;
    __syncthreads();
    int h = tid >> 5, j = tid & 31;
    float p = 0.f;
    for (int e = j; e < 512; e += 32) p = fmaf(qs[e], gb[h * 512 + e], p);
    #pragma unroll
    for (int m = 1; m < 32; m <<= 1) p += __shfl_xor(p, m, 32);
    if (j == 0) qb[n * 8 + h] = p + qbc[h];
    return;
  }
  // ---- M-prep ----
  int b2i = bx - 256;
  int h = b2i >> 6, et = (b2i >> 3) & 7, gt = b2i & 7;
  float (*SA)[68] = (float (*)[68])sm;
  float (*SB)[68] = (float (*)[68])(sm + 17408);
  float* sv0 = (float*)(sm + 34816);
  int r = tid >> 2, cq = (tid & 3) * 16;
  int te = tid & 15, td = tid >> 4;
  const float* wvp = Wv + (long)(h * 64 + r) * 512 + gt * 64 + cq;
  const float* wop = Wo + (long)(et * 64 + r) * 512 + h * 64 + cq;
  #pragma unroll
  for (int c = 0; c < 4; ++c)
    *(f32x4*)&SA[r][cq + 4 * c] = *(const f32x4*)(wvp + 4 * c);   // SA[d][g]
  #pragma unroll
  for (int c = 0; c < 4; ++c) {
    f32x4 x = *(const f32x4*)(wop + 4 * c);                       // coalesced Wo rows
    #pragma unroll
    for (int i = 0; i < 4; ++i) SB[cq + 4 * c + i][r] = x[i];     // SB[d][e] (transposed store)
  }
  if (tid < 64) sv0[tid] = bv[h * 64 + tid];
  __syncthreads();
  float acc[4][4];
  #pragma unroll
  for (int a = 0; a < 4; ++a)
    #pragma unroll
    for (int d = 0; d < 4; ++d) acc[a][d] = 0.f;
  #pragma unroll 4
  for (int jj = 0; jj < 64; ++jj) {
    f32x4 av = *(const f32x4*)&SA[jj][te * 4];
    f32x4 bt = *(const f32x4*)&SB[jj][td * 4];
    #pragma unroll
    for (int a = 0; a < 4; ++a)
      #pragma unroll
      for (int d = 0; d < 4; ++d) acc[a][d] = fmaf(av[a], bt[d], acc[a][d]);
  }
  #pragma unroll
  for (int d = 0; d < 4; ++d) {
    half4 hv = { (_Float16)acc[0][d], (_Float16)acc[1][d],
                 (_Float16)acc[2][d], (_Float16)acc[3][d] };
    *(half4*)(M16 + (long)(et * 64 + td * 4 + d) * 4096 + h * 512 + gt * 64 + te * 4) = hv;
  }
  if (gt == 0 && te == 0) {
    float s0 = 0.f, s1 = 0.f, s2 = 0.f, s3 = 0.f;
    for (int jj = 0; jj < 64; ++jj) {
      f32x4 bt = *(const f32x4*)&SB[jj][td * 4];
      float bb = sv0[jj];
      s0 = fmaf(bt[0], bb, s0); s1 = fmaf(bt[1], bb, s1);
      s2 = fmaf(bt[2], bb, s2); s3 = fmaf(bt[3], bb, s3);
    }
    obo8[h * 512 + et * 64 + td * 4 + 0] = s0;
    obo8[h * 512 + et * 64 + td * 4 + 1] = s1;
    obo8[h * 512 + et * 64 + td * 4 + 2] = s2;
    obo8[h * 512 + et * 64 + td * 4 + 3] = s3;
  }
}

// ---------------- fused streaming attention: 2 stride-8 tiles per block ----------------
// Block (n,g), g in 0..7 owns tiles {g, g+8}. Shorter per-block critical chain (<=2 tiles) than
// 4-tile blocks: 1024 blocks at 2/CU -> scheduler backfills as short blocks retire, moving the
// kernel from chain-bound (~4-tile worst case) toward aggregate-HBM-bound. upv/lsum accumulate in
// registers across the 2 tiles; single pu/pl atomic flush. 2 barriers per tile.
__global__ __launch_bounds__(256) void k_attn(
    const float* __restrict__ t, const int* __restrict__ tlen,
    const _Float16* __restrict__ qk16, const float* __restrict__ qb,
    float* __restrict__ pu, float* __restrict__ pl)
{
  int n = blockIdx.x >> 3, g = blockIdx.x & 7;
  int len = tlen[n];
  if (g * 64 >= len) return;
  int tid = threadIdx.x, wid = tid >> 6, l = tid & 63;
  int fr = l & 15, fo = (l >> 4) * 8;

  __shared__ __align__(16) _Float16 ts[64][TSTR];   // 64.5 KB
  __shared__ __align__(16) _Float16 wst[16][72];    // stride 36 dw: A-read conflict-free

  const float* tn = t + (long)n * SSEQ * TD;
  const _Float16* qn = qk16 + (long)n * 8192 + fr * 512 + fo;
  float qbr = (fr < 8) ? qb[n * 8 + fr] : 0.f;

  f32x4 upv[8];
  #pragma unroll
  for (int dt = 0; dt < 8; ++dt) upv[dt] = (f32x4){0.f, 0.f, 0.f, 0.f};
  float lsum = 0.f;

  for (int jj = 0; jj < 2; ++jj) {
    int base = (g + 8 * jj) * 64;
    if (base >= len) break;                       // block-uniform
    int s1 = base + 64; if (s1 > len) s1 = len;
    if (jj) __syncthreads();                      // protect ts/wst from previous PV readers
    // ---- wave-local stage: rows 16*wid .. 16*wid+15, fp32->fp16, 2-row pipeline ----
    {
      f32x4 a0, a1, b0, b1;
      auto ld = [&](int rr, f32x4& x0, f32x4& x1) {
        int sg = base + 16 * wid + rr;
        if (sg < s1) {
          const float* p = tn + (long)sg * TD;
          x0 = *(const f32x4*)(p + 4 * l);
          x1 = *(const f32x4*)(p + 256 + 4 * l);
        } else {
          x0 = (f32x4){0.f,0.f,0.f,0.f}; x1 = (f32x4){0.f,0.f,0.f,0.f};
        }
      };
      ld(0, a0, a1); ld(1, b0, b1);
      #pragma unroll
      for (int rr = 0; rr < 16; rr += 2) {
        half4 h0 = __builtin_convertvector(a0, half4);
        half4 h1 = __builtin_convertvector(a1, half4);
        int row = 16 * wid + rr;
        if (rr + 2 < 16) ld(rr + 2, a0, a1);
        *(half4*)&ts[row][4 * l] = h0;
        *(half4*)&ts[row][256 + 4 * l] = h1;
        half4 g0 = __builtin_convertvector(b0, half4);
        half4 g1 = __builtin_convertvector(b1, half4);
        if (rr + 3 < 16) ld(rr + 3, b0, b1);
        *(half4*)&ts[row + 1][4 * l] = g0;
        *(half4*)&ts[row + 1][256 + 4 * l] = g1;
      }
    }
    // ---- scores on own rows (wave-internal LDS dependency; no block barrier) ----
    {
      f32x4 acc = (f32x4){0.f, 0.f, 0.f, 0.f};
      __builtin_amdgcn_s_setprio(1);
      #pragma unroll 4
      for (int kt = 0; kt < 16; ++kt) {
        half8 bf = *(const half8*)(qn + kt * 32);
        const _Float16* ap = &ts[16 * wid + fr][kt * 32 + fo];
        half4 alo = *(const half4*)ap;             // b64 pair (row stride 8-aligned)
        half4 ahi = *(const half4*)(ap + 4);
        half8 af = { alo[0], alo[1], alo[2], alo[3], ahi[0], ahi[1], ahi[2], ahi[3] };
        acc = __builtin_amdgcn_mfma_f32_16x16x32_f16(af, bf, acc, 0, 0, 0);
      }
      __builtin_amdgcn_s_setprio(0);
      #pragma unroll
      for (int r = 0; r < 4; ++r) {
        int sl = 16 * wid + (l >> 4) * 4 + r;
        float wv = (fr < 8 && base + sl < s1) ? __expf(acc[r] + qbr) : 0.f;
        wst[fr][sl] = (_Float16)wv;
        lsum += wv;
      }
    }
    __syncthreads();
    // ---- PV via MFMA: wave owns d-range [128*wid, +128); 8 col-tiles x K=64; acc across jj ----
    __builtin_amdgcn_s_setprio(1);
    #pragma unroll
    for (int dt = 0; dt < 8; ++dt) {
      int dcol = 128 * wid + dt * 16 + fr;
      #pragma unroll
      for (int ks = 0; ks < 2; ++ks) {
        half8 af = *(const half8*)&wst[fr][ks * 32 + fo];
        half8 bf;
        #pragma unroll
        for (int jx = 0; jx < 8; ++jx) bf[jx] = ts[ks * 32 + fo + jx][dcol];
        upv[dt] = __builtin_amdgcn_mfma_f32_16x16x32_f16(af, bf, upv[dt], 0, 0, 0);
      }
    }
    __builtin_amdgcn_s_setprio(0);
  }
  // ---- single flush: lane quad q holds heads 4q..4q+3 (valid q<2) ----
  int quad = l >> 4;
  float* pn = pu + (long)n * 4096;
  if (quad < 2) {
    #pragma unroll
    for (int dt = 0; dt < 8; ++dt) {
      int d = 128 * wid + dt * 16 + fr;
      #pragma unroll
      for (int r = 0; r < 4; ++r)
        atomicAdd(&pn[(quad * 4 + r) * 512 + d], upv[dt][r]);
    }
  }
  if (fr < 8) atomicAdd(&pl[n * 8 + fr], lsum);
}

extern "C" void kernel_launch(void* const* d_in, const int* in_sizes, int n_in,
                              void* d_out, int out_size, void* d_ws, size_t ws_size,
                              hipStream_t stream)
{
  const float* v    = (const float*)d_in[0];
  const float* t    = (const float*)d_in[1];
  const int*   tlen = (const int*)d_in[2];
  const float* W1   = (const float*)d_in[3];
  const float* b1   = (const float*)d_in[4];
  const float* W2   = (const float*)d_in[5];
  const float* b2   = (const float*)d_in[6];
  const float* Wq   = (const float*)d_in[7];
  const float* Wk   = (const float*)d_in[8];
  const float* Wv   = (const float*)d_in[9];
  const float* bq   = (const float*)d_in[10];
  const float* bk   = (const float*)d_in[11];
  const float* bv   = (const float*)d_in[12];
  const float* Wo   = (const float*)d_in[13];
  const float* bo   = (const float*)d_in[14];
  float* out = (float*)d_out;

  // ---- workspace layout: fp16 region then fp32 region (~14.5 MB total) ----
  _Float16* hb   = (_Float16*)d_ws;
  _Float16* x16  = hb;                  // 786432   [1536][512]
  _Float16* qk16 = hb + 786432l;        // 1048576  [128][16][512]
  _Float16* G16T = hb + 1835008l;       // 2097152  [8][512 g][512 f]
  _Float16* M16  = hb + 3932160l;       // 2097152  [512 e][8*512 (h,g)]
  float* fb   = (float*)(hb + 6029312l);
  float* vsum = fb;                     // 65536    [128][512] fc2 atomic accum (zeroed)
  float* pu   = fb + 65536l;            // 524288   [128][8][512] (zeroed)
  float* pl   = fb + 589824l;           // 1024     [128][8]  (zeroed)
  float* qb   = fb + 590848l;           // 1024
  float* gb   = fb + 591872l;           // 4096     [8][512]
  float* qbc  = fb + 595968l;           // 16
  float* cvec = fb + 595984l;           // 4096     [8][512]
  float* obo8 = fb + 600080l;           // 4096     [8][512]

  // prep (G/gb/cvec/qbc + zero vsum/pu/pl/qk16-pad) || fc1 GEMM
  k_prepfc1<<<704, 256, 0, stream>>>(Wq, Wk, bq, bk, G16T, gb, qbc, cvec,
                                     fb, qk16, v, W1, b1, x16);
  // fc2 split-K(16): A=x16 fp16 [128x6144], B=W2 fp32 -> atomic accum into vsum (+b2 at sp0)
  // 256 blocks (full GPU) — r4's (16,8)x12 halved parallelism and regressed.
  k_gemm<0,1><<<dim3(16, 16, 1), 256, 0, stream>>>(x16, 6144, 0, W2, 6144, 0,
      b2, nullptr, nullptr, 1.f, 0, 3, vsum, nullptr, 512, 0, 2, 6, 0);
  // qk16 = relu(vsum) @ G16T (+cvec) || out0 = relu(vsum), qb, zero out1 || M16/obo8 prep
  k_qkqb<<<768, 256, 0, stream>>>(vsum, G16T, cvec, gb, qbc, qk16, qb,
                                  out + 65536, out, Wv, Wo, bv, M16, obo8);
  k_attn<<<NB * 8, 256, 0, stream>>>(t, tlen, qk16, qb, pu, pl);
  // attn_out = (pu/pl) @ M16 + bo + obo8[sp], split-K over heads, atomic epilogue -> output 1
  k_gemm<2,0><<<dim3(16, 8, 1), 256, 0, stream>>>(pu, 4096, 0, M16, 4096, 0,
      bo, obo8, pl, 1.f, 0, 3, out + 65536, nullptr, 512, 0, 2, 8, 0);
}